// Round 1
// baseline (2714.317 us; speedup 1.0000x reference)
//
#include <hip/hip_runtime.h>
#include <math.h>

#define N_BATCH 2048
#define T_STEPS 50
#define NCODES  40
#define MH      526
#define AUXD    10
#define E_DIM   256
#define G_DIM   1024   // 4*E
#define BR      8      // batch rows per LSTM block

// ---------------------------------------------------------------------------
// Kernel 1: multi-hot (presence, drop col 0) + concat(aux) @ W_lin + b, ReLU.
// Exploits sparsity: x[nt,e] = relu(b[e] + sum_{distinct c>0} W_lin[c-1,e]
//                                   + sum_a aux[a]*W_lin[526+a,e])
// ---------------------------------------------------------------------------
__global__ __launch_bounds__(256) void k_embed(
    const int* __restrict__ code, const float* __restrict__ aux,
    const float* __restrict__ W_lin, const float* __restrict__ b_lin,
    float* __restrict__ x)
{
    const int nt  = blockIdx.x;          // 0 .. N*T-1
    const int tid = threadIdx.x;         // 0 .. 255  (= output element e)

    __shared__ int   s_codes[NCODES];
    __shared__ int   s_list[NCODES];
    __shared__ float s_aux[AUXD];
    __shared__ int   s_cnt;

    if (tid < NCODES) s_codes[tid] = code[(size_t)nt * NCODES + tid];
    if (tid == 0)     s_cnt = 0;
    if (tid < AUXD)   s_aux[tid] = aux[(size_t)nt * AUXD + tid];
    __syncthreads();

    if (tid < NCODES) {
        int c = s_codes[tid];
        bool keep = (c > 0);
        if (keep) {
            for (int j = 0; j < tid; ++j)
                if (s_codes[j] == c) { keep = false; break; }
        }
        if (keep) { int p = atomicAdd(&s_cnt, 1); s_list[p] = c - 1; }
    }
    __syncthreads();

    const int cnt = s_cnt;
    float acc = b_lin[tid];
    for (int i = 0; i < cnt; ++i)
        acc += W_lin[(size_t)s_list[i] * E_DIM + tid];
    #pragma unroll
    for (int a = 0; a < AUXD; ++a)
        acc += s_aux[a] * W_lin[(size_t)(MH + a) * E_DIM + tid];

    x[(size_t)nt * E_DIM + tid] = fmaxf(acc, 0.f);
}

// ---------------------------------------------------------------------------
// Kernel 2: LSTM over T steps. Each block owns BR batch rows; h,c live in LDS.
// z[r,j] = x_t[r,:]@K[:,j] + h[r,:]@R[:,j] + b[j];  gates [i,f,g,o].
// Captures h at t == length-1 into xlast.
// ---------------------------------------------------------------------------
__global__ __launch_bounds__(512) void k_lstm(
    const float* __restrict__ x, const int* __restrict__ length,
    const float* __restrict__ K, const float* __restrict__ R,
    const float* __restrict__ b, float* __restrict__ xlast)
{
    const int row0 = blockIdx.x * BR;
    const int tid  = threadIdx.x;        // 0..511
    const int j0 = tid, j1 = tid + 512;

    __shared__ __align__(16) float h_s[BR][E_DIM];
    __shared__ __align__(16) float c_s[BR][E_DIM];
    __shared__ __align__(16) float x_s[BR][E_DIM];
    __shared__ float z_s[BR][G_DIM];
    __shared__ int   s_len[BR];
    __shared__ int   s_maxlen;

    for (int i = tid; i < BR * E_DIM; i += 512) {
        (&h_s[0][0])[i] = 0.f;
        (&c_s[0][0])[i] = 0.f;
    }
    if (tid < BR) s_len[tid] = length[row0 + tid];
    __syncthreads();
    if (tid == 0) {
        int m = 0;
        for (int r = 0; r < BR; ++r) m = max(m, s_len[r]);
        s_maxlen = m;
    }
    __syncthreads();
    const int maxlen = s_maxlen;
    const float bb0 = b[j0], bb1 = b[j1];

    for (int t = 0; t < maxlen; ++t) {
        // stage x_t rows
        for (int i = tid; i < BR * E_DIM; i += 512) {
            int r = i >> 8, e = i & 255;
            x_s[r][e] = x[(((size_t)(row0 + r)) * T_STEPS + t) * E_DIM + e];
        }
        __syncthreads();

        float acc0[BR], acc1[BR];
        #pragma unroll
        for (int r = 0; r < BR; ++r) { acc0[r] = 0.f; acc1[r] = 0.f; }

        // x_t @ K
        for (int k4 = 0; k4 < E_DIM; k4 += 4) {
            float4 xv[BR];
            #pragma unroll
            for (int r = 0; r < BR; ++r)
                xv[r] = *reinterpret_cast<const float4*>(&x_s[r][k4]);
            #pragma unroll
            for (int kk = 0; kk < 4; ++kk) {
                float w0 = K[(size_t)(k4 + kk) * G_DIM + j0];
                float w1 = K[(size_t)(k4 + kk) * G_DIM + j1];
                #pragma unroll
                for (int r = 0; r < BR; ++r) {
                    float xe = (&xv[r].x)[kk];
                    acc0[r] += xe * w0; acc1[r] += xe * w1;
                }
            }
        }
        // h @ R
        for (int k4 = 0; k4 < E_DIM; k4 += 4) {
            float4 hv[BR];
            #pragma unroll
            for (int r = 0; r < BR; ++r)
                hv[r] = *reinterpret_cast<const float4*>(&h_s[r][k4]);
            #pragma unroll
            for (int kk = 0; kk < 4; ++kk) {
                float w0 = R[(size_t)(k4 + kk) * G_DIM + j0];
                float w1 = R[(size_t)(k4 + kk) * G_DIM + j1];
                #pragma unroll
                for (int r = 0; r < BR; ++r) {
                    float he = (&hv[r].x)[kk];
                    acc0[r] += he * w0; acc1[r] += he * w1;
                }
            }
        }
        #pragma unroll
        for (int r = 0; r < BR; ++r) {
            z_s[r][j0] = acc0[r] + bb0;
            z_s[r][j1] = acc1[r] + bb1;
        }
        __syncthreads();

        // gate update: 8*256 = 2048 tasks over 512 threads
        for (int i = tid; i < BR * E_DIM; i += 512) {
            int r = i >> 8, e = i & 255;
            float zi = z_s[r][e];
            float zf = z_s[r][E_DIM + e];
            float zg = z_s[r][2 * E_DIM + e];
            float zo = z_s[r][3 * E_DIM + e];
            float ig = 1.f / (1.f + expf(-zi));
            float fg = 1.f / (1.f + expf(-zf));
            float gg = tanhf(zg);
            float og = 1.f / (1.f + expf(-zo));
            float cc = fg * c_s[r][e] + ig * gg;
            float hh = og * tanhf(cc);
            c_s[r][e] = cc;
            h_s[r][e] = hh;
            if (t == s_len[r] - 1)
                xlast[(size_t)(row0 + r) * E_DIM + e] = hh;
        }
        __syncthreads();
    }
}

// ---------------------------------------------------------------------------
// Kernel 3: fv = relu(xlast@W0+b0)@W1+b1, then L2-normalize. One block per n.
// ---------------------------------------------------------------------------
__global__ __launch_bounds__(256) void k_head(
    const float* __restrict__ xlast,
    const float* __restrict__ W0, const float* __restrict__ b0,
    const float* __restrict__ W1, const float* __restrict__ b1,
    float* __restrict__ out)
{
    const int n = blockIdx.x;
    const int j = threadIdx.x;

    __shared__ __align__(16) float xs[E_DIM];
    __shared__ __align__(16) float y0[E_DIM];
    __shared__ float part[4];

    xs[j] = xlast[(size_t)n * E_DIM + j];
    __syncthreads();

    float acc = b0[j];
    for (int k4 = 0; k4 < E_DIM; k4 += 4) {
        float4 xv = *reinterpret_cast<const float4*>(&xs[k4]);
        #pragma unroll
        for (int kk = 0; kk < 4; ++kk)
            acc += (&xv.x)[kk] * W0[(size_t)(k4 + kk) * E_DIM + j];
    }
    y0[j] = fmaxf(acc, 0.f);
    __syncthreads();

    acc = b1[j];
    for (int k4 = 0; k4 < E_DIM; k4 += 4) {
        float4 yv = *reinterpret_cast<const float4*>(&y0[k4]);
        #pragma unroll
        for (int kk = 0; kk < 4; ++kk)
            acc += (&yv.x)[kk] * W1[(size_t)(k4 + kk) * E_DIM + j];
    }

    float sq = acc * acc;
    #pragma unroll
    for (int off = 32; off > 0; off >>= 1)
        sq += __shfl_xor(sq, off, 64);
    if ((j & 63) == 0) part[j >> 6] = sq;
    __syncthreads();
    float total = part[0] + part[1] + part[2] + part[3];

    out[(size_t)n * E_DIM + j] = acc * rsqrtf(total);
}

// ---------------------------------------------------------------------------
extern "C" void kernel_launch(void* const* d_in, const int* in_sizes, int n_in,
                              void* d_out, int out_size, void* d_ws, size_t ws_size,
                              hipStream_t stream) {
    const int*   code   = (const int*)  d_in[0];
    const float* aux    = (const float*)d_in[1];
    const int*   length = (const int*)  d_in[2];
    // d_in[3] = is_training (ignored, inference path)
    const float* W_lin  = (const float*)d_in[4];
    const float* b_lin  = (const float*)d_in[5];
    const float* K      = (const float*)d_in[6];
    const float* R      = (const float*)d_in[7];
    const float* b      = (const float*)d_in[8];
    const float* W0     = (const float*)d_in[9];
    const float* b0     = (const float*)d_in[10];
    const float* W1     = (const float*)d_in[11];
    const float* b1     = (const float*)d_in[12];
    float* out = (float*)d_out;

    float* x     = (float*)d_ws;                          // N*T*E f32
    float* xlast = x + (size_t)N_BATCH * T_STEPS * E_DIM; // N*E f32

    k_embed<<<N_BATCH * T_STEPS, 256, 0, stream>>>(code, aux, W_lin, b_lin, x);
    k_lstm <<<N_BATCH / BR,      512, 0, stream>>>(x, length, K, R, b, xlast);
    k_head <<<N_BATCH,           256, 0, stream>>>(xlast, W0, b0, W1, b1, out);
}

// Round 2
// 1914.230 us; speedup vs baseline: 1.4180x; 1.4180x over previous
//
#include <hip/hip_runtime.h>
#include <hip/hip_bf16.h>
#include <math.h>

#define N_BATCH 2048
#define T_STEPS 50
#define NCODES  40
#define MH      526
#define AUXD    10
#define E_DIM   256
#define G_DIM   1024   // 4*E
#define BM      16     // batch rows per LSTM block

typedef __attribute__((ext_vector_type(8))) short short8;   // 8 bf16 = 4 VGPR
typedef __attribute__((ext_vector_type(4))) float f32x4;

__device__ __forceinline__ short f2bf(float f) {
    __hip_bfloat16 h = __float2bfloat16(f);
    return *reinterpret_cast<short*>(&h);
}
__device__ __forceinline__ float sigf(float x) {
    return 1.f / (1.f + __expf(-x));
}
__device__ __forceinline__ float tanhfast(float x) {
    // 2/(1+exp(-2x)) - 1 ; saturates correctly for |x| large
    return 2.f / (1.f + __expf(-2.f * x)) - 1.f;
}

// ---------------------------------------------------------------------------
// Kernel 1: sparse multi-hot + aux @ W_lin + b, ReLU. Output bf16.
// ---------------------------------------------------------------------------
__global__ __launch_bounds__(256) void k_embed(
    const int* __restrict__ code, const float* __restrict__ aux,
    const float* __restrict__ W_lin, const float* __restrict__ b_lin,
    short* __restrict__ x)
{
    const int nt  = blockIdx.x;          // 0 .. N*T-1
    const int tid = threadIdx.x;         // output element e

    __shared__ int   s_codes[NCODES];
    __shared__ int   s_list[NCODES];
    __shared__ float s_aux[AUXD];
    __shared__ int   s_cnt;

    if (tid < NCODES) s_codes[tid] = code[(size_t)nt * NCODES + tid];
    if (tid == 0)     s_cnt = 0;
    if (tid < AUXD)   s_aux[tid] = aux[(size_t)nt * AUXD + tid];
    __syncthreads();

    if (tid < NCODES) {
        int c = s_codes[tid];
        bool keep = (c > 0);
        if (keep) {
            for (int j = 0; j < tid; ++j)
                if (s_codes[j] == c) { keep = false; break; }
        }
        if (keep) { int p = atomicAdd(&s_cnt, 1); s_list[p] = c - 1; }
    }
    __syncthreads();

    const int cnt = s_cnt;
    float acc = b_lin[tid];
    for (int i = 0; i < cnt; ++i)
        acc += W_lin[(size_t)s_list[i] * E_DIM + tid];
    #pragma unroll
    for (int a = 0; a < AUXD; ++a)
        acc += s_aux[a] * W_lin[(size_t)(MH + a) * E_DIM + tid];

    x[(size_t)nt * E_DIM + tid] = f2bf(fmaxf(acc, 0.f));
}

// ---------------------------------------------------------------------------
// Kernel 2: weight prep. Wt[n][k] (bf16, k=0..511) = [K;R][k][n], transposed
// via LDS tile so both global reads and writes are coalesced.
// ---------------------------------------------------------------------------
__global__ __launch_bounds__(256) void k_prep(
    const float* __restrict__ K, const float* __restrict__ R,
    short* __restrict__ Wt)
{
    const int tid = threadIdx.x;
    const int kt = blockIdx.x & 7;       // k0 = kt*64  (512 total k)
    const int nt = blockIdx.x >> 3;      // n0 = nt*64  (1024 total n)
    const int k0 = kt * 64, n0 = nt * 64;

    __shared__ float tile[64][65];

    const int nloc_r = tid & 63;
    for (int kloc = tid >> 6; kloc < 64; kloc += 4) {
        const int k = k0 + kloc;
        float v = (k < 256) ? K[(size_t)k * G_DIM + n0 + nloc_r]
                            : R[(size_t)(k - 256) * G_DIM + n0 + nloc_r];
        tile[kloc][nloc_r] = v;
    }
    __syncthreads();

    const int nloc = tid >> 2;
    const int kc   = (tid & 3) * 16;
    int* dst = (int*)(Wt + (size_t)(n0 + nloc) * 512 + k0 + kc);
    #pragma unroll
    for (int j = 0; j < 8; ++j) {
        int lo = f2bf(tile[kc + 2 * j][nloc]) & 0xffff;
        int hi = f2bf(tile[kc + 2 * j + 1][nloc]) & 0xffff;
        dst[j] = lo | (hi << 16);
    }
}

// ---------------------------------------------------------------------------
// Kernel 3: MFMA LSTM. 128 blocks x 512 threads (8 waves). Block owns 16
// batch rows. Per step: z = [x_t | h] @ Wt^T via mfma_f32_16x16x32_bf16,
// wave w owns cols {g*256 + w*32 + eb*16 + lane%16} for all gates g ->
// gates computed entirely in registers; only h round-trips LDS (bf16).
// ---------------------------------------------------------------------------
__global__ __launch_bounds__(512) void k_lstm(
    const short* __restrict__ x, const int* __restrict__ length,
    const short* __restrict__ Wt, const float* __restrict__ b,
    float* __restrict__ xlast)
{
    const int tid  = threadIdx.x;
    const int w    = tid >> 6;
    const int lane = tid & 63;
    const int lr   = lane & 15;
    const int p    = lane >> 4;
    const int r0   = blockIdx.x * BM;

    __shared__ __align__(16) short h_s[BM][264];   // 264 = 256 + 8 pad (16B)
    __shared__ int s_len[BM];
    __shared__ int s_maxlen;

    for (int i = tid; i < BM * 264; i += 512) (&h_s[0][0])[i] = 0;
    if (tid < BM) s_len[tid] = length[r0 + tid];
    __syncthreads();
    if (tid == 0) {
        int m = 0;
        for (int r2 = 0; r2 < BM; ++r2) m = max(m, s_len[r2]);
        s_maxlen = m;
    }
    __syncthreads();
    const int maxlen = s_maxlen;

    int len_r[4];
    #pragma unroll
    for (int r2 = 0; r2 < 4; ++r2) len_r[r2] = s_len[p * 4 + r2];

    const int ecol = w * 32 + lr;        // e for eb=0; eb adds 16
    float bias[8];
    #pragma unroll
    for (int eb = 0; eb < 2; ++eb)
        #pragma unroll
        for (int g = 0; g < 4; ++g)
            bias[eb * 4 + g] = b[g * 256 + ecol + eb * 16];

    float creg[8];
    #pragma unroll
    for (int i = 0; i < 8; ++i) creg[i] = 0.f;

    const short* xrow  = x + (size_t)(r0 + lr) * T_STEPS * E_DIM + p * 8;
    const short* wbase = Wt + (size_t)(w * 32 + lr) * 512 + p * 8;

    for (int t = 0; t < maxlen; ++t) {
        f32x4 acc[8];
        #pragma unroll
        for (int i = 0; i < 8; ++i) acc[i] = (f32x4){0.f, 0.f, 0.f, 0.f};

        // ---- h-half of K (k in [256,512)) : A from LDS ----
        #pragma unroll
        for (int kk = 0; kk < 8; ++kk) {
            short8 a = *(const short8*)(&h_s[lr][kk * 32 + p * 8]);
            #pragma unroll
            for (int nf = 0; nf < 8; ++nf) {
                const int eb = nf >> 2, g = nf & 3;
                short8 bf = *(const short8*)(wbase +
                    (size_t)(g * 256 + eb * 16) * 512 + 256 + kk * 32);
                acc[nf] = __builtin_amdgcn_mfma_f32_16x16x32_bf16(a, bf, acc[nf], 0, 0, 0);
            }
        }
        // ---- x-half of K (k in [0,256)) : A from global ----
        const short* xp = xrow + (size_t)t * E_DIM;
        #pragma unroll
        for (int kk = 0; kk < 8; ++kk) {
            short8 a = *(const short8*)(xp + kk * 32);
            #pragma unroll
            for (int nf = 0; nf < 8; ++nf) {
                const int eb = nf >> 2, g = nf & 3;
                short8 bf = *(const short8*)(wbase +
                    (size_t)(g * 256 + eb * 16) * 512 + kk * 32);
                acc[nf] = __builtin_amdgcn_mfma_f32_16x16x32_bf16(a, bf, acc[nf], 0, 0, 0);
            }
        }
        __syncthreads();   // all h_s reads done before gate writes

        // ---- gates fully in registers ----
        #pragma unroll
        for (int eb = 0; eb < 2; ++eb) {
            #pragma unroll
            for (int r2 = 0; r2 < 4; ++r2) {
                float zi = acc[eb * 4 + 0][r2] + bias[eb * 4 + 0];
                float zf = acc[eb * 4 + 1][r2] + bias[eb * 4 + 1];
                float zg = acc[eb * 4 + 2][r2] + bias[eb * 4 + 2];
                float zo = acc[eb * 4 + 3][r2] + bias[eb * 4 + 3];
                float ig = sigf(zi), fg = sigf(zf);
                float gg = tanhfast(zg), og = sigf(zo);
                float cc = fg * creg[eb * 4 + r2] + ig * gg;
                float hh = og * tanhfast(cc);
                creg[eb * 4 + r2] = cc;
                const int m = p * 4 + r2;
                const int e = ecol + eb * 16;
                h_s[m][e] = f2bf(hh);
                if (t == len_r[r2] - 1)
                    xlast[(size_t)(r0 + m) * E_DIM + e] = hh;
            }
        }
        __syncthreads();   // h_s ready for next step
    }
}

// ---------------------------------------------------------------------------
// Kernel 4: head MLP + L2 normalize. One block per n.
// ---------------------------------------------------------------------------
__global__ __launch_bounds__(256) void k_head(
    const float* __restrict__ xlast,
    const float* __restrict__ W0, const float* __restrict__ b0,
    const float* __restrict__ W1, const float* __restrict__ b1,
    float* __restrict__ out)
{
    const int n = blockIdx.x;
    const int j = threadIdx.x;

    __shared__ __align__(16) float xs[E_DIM];
    __shared__ __align__(16) float y0[E_DIM];
    __shared__ float part[4];

    xs[j] = xlast[(size_t)n * E_DIM + j];
    __syncthreads();

    float acc = b0[j];
    for (int k4 = 0; k4 < E_DIM; k4 += 4) {
        float4 xv = *reinterpret_cast<const float4*>(&xs[k4]);
        #pragma unroll
        for (int kk = 0; kk < 4; ++kk)
            acc += (&xv.x)[kk] * W0[(size_t)(k4 + kk) * E_DIM + j];
    }
    y0[j] = fmaxf(acc, 0.f);
    __syncthreads();

    acc = b1[j];
    for (int k4 = 0; k4 < E_DIM; k4 += 4) {
        float4 yv = *reinterpret_cast<const float4*>(&y0[k4]);
        #pragma unroll
        for (int kk = 0; kk < 4; ++kk)
            acc += (&yv.x)[kk] * W1[(size_t)(k4 + kk) * E_DIM + j];
    }

    float sq = acc * acc;
    #pragma unroll
    for (int off = 32; off > 0; off >>= 1)
        sq += __shfl_xor(sq, off, 64);
    if ((j & 63) == 0) part[j >> 6] = sq;
    __syncthreads();
    float total = part[0] + part[1] + part[2] + part[3];

    out[(size_t)n * E_DIM + j] = acc * rsqrtf(total);
}

// ---------------------------------------------------------------------------
extern "C" void kernel_launch(void* const* d_in, const int* in_sizes, int n_in,
                              void* d_out, int out_size, void* d_ws, size_t ws_size,
                              hipStream_t stream) {
    const int*   code   = (const int*)  d_in[0];
    const float* aux    = (const float*)d_in[1];
    const int*   length = (const int*)  d_in[2];
    // d_in[3] = is_training (ignored)
    const float* W_lin  = (const float*)d_in[4];
    const float* b_lin  = (const float*)d_in[5];
    const float* K      = (const float*)d_in[6];
    const float* R      = (const float*)d_in[7];
    const float* b      = (const float*)d_in[8];
    const float* W0     = (const float*)d_in[9];
    const float* b0     = (const float*)d_in[10];
    const float* W1     = (const float*)d_in[11];
    const float* b1     = (const float*)d_in[12];
    float* out = (float*)d_out;

    // workspace layout (all 16B aligned)
    short* x     = (short*)d_ws;                              // 52,428,800 B
    short* Wt    = (short*)((char*)d_ws + 52428800);          //  1,048,576 B
    float* xlast = (float*)((char*)d_ws + 53477376);          //  2,097,152 B

    k_embed<<<N_BATCH * T_STEPS, 256, 0, stream>>>(code, aux, W_lin, b_lin, x);
    k_prep <<<128,              256, 0, stream>>>(K, R, Wt);
    k_lstm <<<N_BATCH / BM,     512, 0, stream>>>(x, length, Wt, b, xlast);
    k_head <<<N_BATCH,          256, 0, stream>>>(xlast, W0, b0, W1, b1, out);
}

// Round 3
// 984.915 us; speedup vs baseline: 2.7559x; 1.9435x over previous
//
#include <hip/hip_runtime.h>
#include <hip/hip_bf16.h>
#include <math.h>

#define N_BATCH 2048
#define T_STEPS 50
#define NCODES  40
#define MH      526
#define AUXD    10
#define E_DIM   256
#define G_DIM   1024   // 4*E
#define BM      16     // batch rows per recurrence block
#define TCHUNK  10     // time steps per chunk (5 chunks)

typedef __attribute__((ext_vector_type(8))) short short8;   // 8 bf16 = 4 VGPR
typedef __attribute__((ext_vector_type(4))) float f32x4;

__device__ __forceinline__ short f2bf(float f) {
    __hip_bfloat16 h = __float2bfloat16(f);
    return *reinterpret_cast<short*>(&h);
}
__device__ __forceinline__ float bf2f(unsigned short u) {
    return __uint_as_float(((unsigned int)u) << 16);
}
__device__ __forceinline__ float sigf(float x) {
    return 1.f / (1.f + __expf(-x));
}
__device__ __forceinline__ float tanhfast(float x) {
    return 2.f / (1.f + __expf(-2.f * x)) - 1.f;
}

// ---------------------------------------------------------------------------
// Kernel 0: W_lin f32 -> bf16 (halves embed gather traffic)
// ---------------------------------------------------------------------------
__global__ __launch_bounds__(256) void k_prepw(
    const float* __restrict__ W_lin, short* __restrict__ Wl)
{
    const int i = blockIdx.x * 256 + threadIdx.x;   // grid = 536 blocks
    Wl[i] = f2bf(W_lin[i]);
}

// ---------------------------------------------------------------------------
// Kernel 1: sparse multi-hot + aux @ W_lin + b, ReLU. Output bf16.
// ---------------------------------------------------------------------------
__global__ __launch_bounds__(256) void k_embed(
    const int* __restrict__ code, const float* __restrict__ aux,
    const short* __restrict__ Wl, const float* __restrict__ b_lin,
    short* __restrict__ x)
{
    const int nt  = blockIdx.x;          // 0 .. N*T-1
    const int tid = threadIdx.x;         // output element e

    __shared__ int   s_codes[NCODES];
    __shared__ int   s_list[NCODES];
    __shared__ float s_aux[AUXD];
    __shared__ int   s_cnt;

    if (tid < NCODES) s_codes[tid] = code[(size_t)nt * NCODES + tid];
    if (tid == 0)     s_cnt = 0;
    if (tid < AUXD)   s_aux[tid] = aux[(size_t)nt * AUXD + tid];
    __syncthreads();

    if (tid < NCODES) {
        int c = s_codes[tid];
        bool keep = (c > 0);
        if (keep) {
            for (int j = 0; j < tid; ++j)
                if (s_codes[j] == c) { keep = false; break; }
        }
        if (keep) { int pp = atomicAdd(&s_cnt, 1); s_list[pp] = c - 1; }
    }
    __syncthreads();

    const int cnt = s_cnt;
    float acc = b_lin[tid];
    for (int i = 0; i < cnt; ++i)
        acc += bf2f((unsigned short)Wl[(size_t)s_list[i] * E_DIM + tid]);
    #pragma unroll
    for (int a = 0; a < AUXD; ++a)
        acc += s_aux[a] * bf2f((unsigned short)Wl[(size_t)(MH + a) * E_DIM + tid]);

    x[(size_t)nt * E_DIM + tid] = f2bf(fmaxf(acc, 0.f));
}

// ---------------------------------------------------------------------------
// Kernel 2: weight prep. Wt[n][k] (bf16, k=0..511) = [K;R][k][n].
// ---------------------------------------------------------------------------
__global__ __launch_bounds__(256) void k_prep(
    const float* __restrict__ K, const float* __restrict__ R,
    short* __restrict__ Wt)
{
    const int tid = threadIdx.x;
    const int kt = blockIdx.x & 7;       // k0 = kt*64
    const int nt = blockIdx.x >> 3;      // n0 = nt*64
    const int k0 = kt * 64, n0 = nt * 64;

    __shared__ float tile[64][65];

    const int nloc_r = tid & 63;
    for (int kloc = tid >> 6; kloc < 64; kloc += 4) {
        const int k = k0 + kloc;
        float v = (k < 256) ? K[(size_t)k * G_DIM + n0 + nloc_r]
                            : R[(size_t)(k - 256) * G_DIM + n0 + nloc_r];
        tile[kloc][nloc_r] = v;
    }
    __syncthreads();

    const int nloc = tid >> 2;
    const int kc   = (tid & 3) * 16;
    int* dst = (int*)(Wt + (size_t)(n0 + nloc) * 512 + k0 + kc);
    #pragma unroll
    for (int j = 0; j < 8; ++j) {
        int lo = f2bf(tile[kc + 2 * j][nloc]) & 0xffff;
        int hi = f2bf(tile[kc + 2 * j + 1][nloc]) & 0xffff;
        dst[j] = lo | (hi << 16);
    }
}

// ---------------------------------------------------------------------------
// Kernel 3: xz GEMM for one t-chunk.  M = 2048*TCHUNK rows (m -> n=m/10,
// t=t0+m%10), N = 1024, K = 256.  Tile 128x256, 8 waves (2x4), LDS-staged.
// Output bf16 xzb[m][1024].
// ---------------------------------------------------------------------------
__global__ __launch_bounds__(512) void k_xz(
    const short* __restrict__ x, const short* __restrict__ Wt,
    short* __restrict__ xzb, int t0)
{
    const int tid  = threadIdx.x;
    const int wave = tid >> 6;
    const int wr   = wave >> 2;          // 0..1  (64-row half)
    const int wc   = wave & 3;           // 0..3  (64-col quarter)
    const int lane = tid & 63;
    const int lr   = lane & 15;
    const int p    = lane >> 4;

    const int mt = blockIdx.x >> 2;
    const int ntile = blockIdx.x & 3;
    const int m0 = mt * 128;
    const int n0 = ntile * 256;

    __shared__ __align__(16) short Asm[128 * 40];
    __shared__ __align__(16) short Bsm[256 * 40];

    // A staging address (one 16B chunk per thread per kb)
    const int ar = tid >> 2;
    const int akc = (tid & 3) * 8;
    const int am = m0 + ar;
    const int an = am / TCHUNK;
    const int att = t0 + (am - an * TCHUNK);
    const size_t xoff = (size_t)(an * T_STEPS + att) * E_DIM + akc;

    f32x4 acc[4][4];
    #pragma unroll
    for (int rb = 0; rb < 4; ++rb)
        #pragma unroll
        for (int cb = 0; cb < 4; ++cb)
            acc[rb][cb] = (f32x4){0.f, 0.f, 0.f, 0.f};

    for (int kb = 0; kb < 8; ++kb) {
        if (kb > 0) __syncthreads();
        // stage A: 128 x 32
        *(int4*)&Asm[ar * 40 + akc] = *(const int4*)(x + xoff + kb * 32);
        // stage B: 256 x 32 (2 chunks per thread)
        #pragma unroll
        for (int q = 0; q < 2; ++q) {
            const int idx = tid * 2 + q;
            const int c = idx >> 2;
            const int kc = (idx & 3) * 8;
            *(int4*)&Bsm[c * 40 + kc] =
                *(const int4*)(Wt + (size_t)(n0 + c) * 512 + kb * 32 + kc);
        }
        __syncthreads();

        short8 af[4], bf[4];
        #pragma unroll
        for (int rb = 0; rb < 4; ++rb)
            af[rb] = *(const short8*)&Asm[(wr * 64 + rb * 16 + lr) * 40 + p * 8];
        #pragma unroll
        for (int cb = 0; cb < 4; ++cb)
            bf[cb] = *(const short8*)&Bsm[(wc * 64 + cb * 16 + lr) * 40 + p * 8];
        #pragma unroll
        for (int rb = 0; rb < 4; ++rb)
            #pragma unroll
            for (int cb = 0; cb < 4; ++cb)
                acc[rb][cb] = __builtin_amdgcn_mfma_f32_16x16x32_bf16(
                    af[rb], bf[cb], acc[rb][cb], 0, 0, 0);
    }

    #pragma unroll
    for (int rb = 0; rb < 4; ++rb) {
        #pragma unroll
        for (int cb = 0; cb < 4; ++cb) {
            #pragma unroll
            for (int rr = 0; rr < 4; ++rr) {
                const int rowm = m0 + wr * 64 + rb * 16 + p * 4 + rr;
                const int col  = n0 + wc * 64 + cb * 16 + lr;
                xzb[(size_t)rowm * G_DIM + col] = f2bf(acc[rb][cb][rr]);
            }
        }
    }
}

// ---------------------------------------------------------------------------
// Kernel 4: recurrence for one t-chunk. 128 blocks x 512 thr (8 waves),
// BM=16 rows/block. z = xz + h@R (MFMA, B-frags double-buffered from L2),
// gates in registers, h through LDS. State (h bf16, c f32) in ws.
// ---------------------------------------------------------------------------
__global__ __launch_bounds__(512) void k_rec(
    const short* __restrict__ xz, const int* __restrict__ length,
    const short* __restrict__ Wt, const float* __restrict__ b,
    short* __restrict__ h_state, float* __restrict__ c_state,
    float* __restrict__ xlast, int t0)
{
    const int tid  = threadIdx.x;
    const int w    = tid >> 6;
    const int lane = tid & 63;
    const int lr   = lane & 15;
    const int p    = lane >> 4;
    const int r0   = blockIdx.x * BM;

    __shared__ __align__(16) short h_s[BM][264];
    __shared__ int s_len[BM];
    __shared__ int s_maxlen;

    if (tid < BM) s_len[tid] = length[r0 + tid];
    __syncthreads();
    if (tid == 0) {
        int m = 0;
        for (int r2 = 0; r2 < BM; ++r2) m = max(m, s_len[r2]);
        s_maxlen = m;
    }
    __syncthreads();
    const int mlen = s_maxlen;
    if (mlen <= t0) return;                        // block finished earlier
    const int steps = min(TCHUNK, mlen - t0);

    const int ecol = w * 32 + lr;

    // ---- load / init state ----
    float creg[8];
    if (t0 == 0) {
        for (int i = tid; i < BM * 264; i += 512) (&h_s[0][0])[i] = 0;
        #pragma unroll
        for (int i = 0; i < 8; ++i) creg[i] = 0.f;
    } else {
        for (int i = tid; i < BM * E_DIM; i += 512) {
            int r2 = i >> 8, e = i & 255;
            h_s[r2][e] = h_state[(size_t)(r0 + r2) * E_DIM + e];
        }
        #pragma unroll
        for (int eb = 0; eb < 2; ++eb)
            #pragma unroll
            for (int rr = 0; rr < 4; ++rr)
                creg[eb * 4 + rr] =
                    c_state[(size_t)(r0 + p * 4 + rr) * E_DIM + ecol + eb * 16];
    }
    __syncthreads();

    int len_r[4];
    #pragma unroll
    for (int rr = 0; rr < 4; ++rr) len_r[rr] = s_len[p * 4 + rr];

    float bias[8];
    #pragma unroll
    for (int eb = 0; eb < 2; ++eb)
        #pragma unroll
        for (int g = 0; g < 4; ++g)
            bias[eb * 4 + g] = b[g * 256 + ecol + eb * 16];

    const short* wb = Wt + (size_t)(w * 32 + lr) * 512 + 256 + p * 8; // R-half

    for (int tl = 0; tl < steps; ++tl) {
        const int t = t0 + tl;

        // a-frags (h) from LDS
        short8 a[8];
        #pragma unroll
        for (int kk = 0; kk < 8; ++kk)
            a[kk] = *(const short8*)(&h_s[lr][kk * 32 + p * 8]);

        // acc init from xz (bf16 -> f32)
        f32x4 acc[8];
        #pragma unroll
        for (int f = 0; f < 8; ++f) {
            const int eb = f >> 2, g = f & 3;
            #pragma unroll
            for (int rr = 0; rr < 4; ++rr) {
                const size_t m = (size_t)(r0 + p * 4 + rr) * TCHUNK + tl;
                acc[f][rr] = bf2f((unsigned short)
                    xz[m * G_DIM + g * 256 + w * 32 + eb * 16 + lr]);
            }
        }

        // h @ R with double-buffered B fragments
        short8 bA[8], bB[8];
        #pragma unroll
        for (int f = 0; f < 8; ++f) {
            const int eb = f >> 2, g = f & 3;
            bA[f] = *(const short8*)(wb + (size_t)(g * 256 + eb * 16) * 512);
        }
        #pragma unroll
        for (int kp = 0; kp < 4; ++kp) {
            const int k_e = kp * 2, k_o = kp * 2 + 1;
            #pragma unroll
            for (int f = 0; f < 8; ++f) {
                const int eb = f >> 2, g = f & 3;
                bB[f] = *(const short8*)(wb +
                    (size_t)(g * 256 + eb * 16) * 512 + k_o * 32);
            }
            #pragma unroll
            for (int f = 0; f < 8; ++f)
                acc[f] = __builtin_amdgcn_mfma_f32_16x16x32_bf16(
                    a[k_e], bA[f], acc[f], 0, 0, 0);
            if (kp < 3) {
                #pragma unroll
                for (int f = 0; f < 8; ++f) {
                    const int eb = f >> 2, g = f & 3;
                    bA[f] = *(const short8*)(wb +
                        (size_t)(g * 256 + eb * 16) * 512 + (k_e + 2) * 32);
                }
            }
            #pragma unroll
            for (int f = 0; f < 8; ++f)
                acc[f] = __builtin_amdgcn_mfma_f32_16x16x32_bf16(
                    a[k_o], bB[f], acc[f], 0, 0, 0);
        }

        // gates (registers only)
        short hnew[8];
        float hout[8];
        #pragma unroll
        for (int eb = 0; eb < 2; ++eb) {
            #pragma unroll
            for (int rr = 0; rr < 4; ++rr) {
                float zi = acc[eb * 4 + 0][rr] + bias[eb * 4 + 0];
                float zf = acc[eb * 4 + 1][rr] + bias[eb * 4 + 1];
                float zg = acc[eb * 4 + 2][rr] + bias[eb * 4 + 2];
                float zo = acc[eb * 4 + 3][rr] + bias[eb * 4 + 3];
                float ig = sigf(zi), fg = sigf(zf);
                float gg = tanhfast(zg), og = sigf(zo);
                float cc = fg * creg[eb * 4 + rr] + ig * gg;
                float hh = og * tanhfast(cc);
                creg[eb * 4 + rr] = cc;
                hnew[eb * 4 + rr] = f2bf(hh);
                hout[eb * 4 + rr] = hh;
            }
        }
        __syncthreads();   // all h_s reads (a-frags) done in all waves
        #pragma unroll
        for (int eb = 0; eb < 2; ++eb) {
            #pragma unroll
            for (int rr = 0; rr < 4; ++rr) {
                const int m = p * 4 + rr;
                const int e = ecol + eb * 16;
                h_s[m][e] = hnew[eb * 4 + rr];
                if (t == len_r[rr] - 1)
                    xlast[(size_t)(r0 + m) * E_DIM + e] = hout[eb * 4 + rr];
            }
        }
        __syncthreads();
    }

    // ---- save state ----
    for (int i = tid; i < BM * E_DIM; i += 512) {
        int r2 = i >> 8, e = i & 255;
        h_state[(size_t)(r0 + r2) * E_DIM + e] = h_s[r2][e];
    }
    #pragma unroll
    for (int eb = 0; eb < 2; ++eb)
        #pragma unroll
        for (int rr = 0; rr < 4; ++rr)
            c_state[(size_t)(r0 + p * 4 + rr) * E_DIM + ecol + eb * 16] =
                creg[eb * 4 + rr];
}

// ---------------------------------------------------------------------------
// Kernel 5: head MLP + L2 normalize. One block per n.
// ---------------------------------------------------------------------------
__global__ __launch_bounds__(256) void k_head(
    const float* __restrict__ xlast,
    const float* __restrict__ W0, const float* __restrict__ b0,
    const float* __restrict__ W1, const float* __restrict__ b1,
    float* __restrict__ out)
{
    const int n = blockIdx.x;
    const int j = threadIdx.x;

    __shared__ __align__(16) float xs[E_DIM];
    __shared__ __align__(16) float y0[E_DIM];
    __shared__ float part[4];

    xs[j] = xlast[(size_t)n * E_DIM + j];
    __syncthreads();

    float acc = b0[j];
    for (int k4 = 0; k4 < E_DIM; k4 += 4) {
        float4 xv = *reinterpret_cast<const float4*>(&xs[k4]);
        #pragma unroll
        for (int kk = 0; kk < 4; ++kk)
            acc += (&xv.x)[kk] * W0[(size_t)(k4 + kk) * E_DIM + j];
    }
    y0[j] = fmaxf(acc, 0.f);
    __syncthreads();

    acc = b1[j];
    for (int k4 = 0; k4 < E_DIM; k4 += 4) {
        float4 yv = *reinterpret_cast<const float4*>(&y0[k4]);
        #pragma unroll
        for (int kk = 0; kk < 4; ++kk)
            acc += (&yv.x)[kk] * W1[(size_t)(k4 + kk) * E_DIM + j];
    }

    float sq = acc * acc;
    #pragma unroll
    for (int off = 32; off > 0; off >>= 1)
        sq += __shfl_xor(sq, off, 64);
    if ((j & 63) == 0) part[j >> 6] = sq;
    __syncthreads();
    float total = part[0] + part[1] + part[2] + part[3];

    out[(size_t)n * E_DIM + j] = acc * rsqrtf(total);
}

// ---------------------------------------------------------------------------
extern "C" void kernel_launch(void* const* d_in, const int* in_sizes, int n_in,
                              void* d_out, int out_size, void* d_ws, size_t ws_size,
                              hipStream_t stream) {
    const int*   code   = (const int*)  d_in[0];
    const float* aux    = (const float*)d_in[1];
    const int*   length = (const int*)  d_in[2];
    // d_in[3] = is_training (ignored)
    const float* W_lin  = (const float*)d_in[4];
    const float* b_lin  = (const float*)d_in[5];
    const float* K      = (const float*)d_in[6];
    const float* R      = (const float*)d_in[7];
    const float* b      = (const float*)d_in[8];
    const float* W0     = (const float*)d_in[9];
    const float* b0     = (const float*)d_in[10];
    const float* W1     = (const float*)d_in[11];
    const float* b1     = (const float*)d_in[12];
    float* out = (float*)d_out;

    // workspace layout (bytes, all 16B aligned); total ~96.3 MB
    char* ws = (char*)d_ws;
    short* x       = (short*)(ws + 0);            //  52,428,800
    short* Wt      = (short*)(ws + 52428800);     //   1,048,576
    short* Wl      = (short*)(ws + 53477376);     //     274,432
    float* xlast   = (float*)(ws + 53751808);     //   2,097,152
    short* h_state = (short*)(ws + 55848960);     //   1,048,576
    float* c_state = (float*)(ws + 56897536);     //   2,097,152
    short* xzb     = (short*)(ws + 58994688);     //  41,943,040

    k_prepw<<<(MH + AUXD), 256, 0, stream>>>(W_lin, Wl);
    k_prep <<<128, 256, 0, stream>>>(K, R, Wt);
    k_embed<<<N_BATCH * T_STEPS, 256, 0, stream>>>(code, aux, Wl, b_lin, x);

    for (int c = 0; c < T_STEPS / TCHUNK; ++c) {
        const int t0 = c * TCHUNK;
        k_xz <<<(N_BATCH * TCHUNK / 128) * 4, 512, 0, stream>>>(x, Wt, xzb, t0);
        k_rec<<<N_BATCH / BM, 512, 0, stream>>>(xzb, length, Wt, b,
                                                h_state, c_state, xlast, t0);
    }

    k_head<<<N_BATCH, 256, 0, stream>>>(xlast, W0, b0, W1, b1, out);
}

// Round 4
// 971.335 us; speedup vs baseline: 2.7944x; 1.0140x over previous
//
#include <hip/hip_runtime.h>
#include <hip/hip_bf16.h>
#include <math.h>

#define N_BATCH 2048
#define T_STEPS 50
#define NCODES  40
#define MH      526
#define AUXD    10
#define WLROWS  536    // MH + AUXD
#define KPAD    544    // WLROWS padded to 17*32
#define E_DIM   256
#define G_DIM   1024   // 4*E
#define BM      16     // batch rows per recurrence block
#define TCHUNK  10     // time steps per chunk (5 chunks)
#define MBLK    32     // (n,t) rows per fused block

typedef __attribute__((ext_vector_type(8))) short short8;   // 8 bf16 = 4 VGPR
typedef __attribute__((ext_vector_type(4))) float f32x4;

__device__ __forceinline__ short f2bf(float f) {
    __hip_bfloat16 h = __float2bfloat16(f);
    return *reinterpret_cast<short*>(&h);
}
__device__ __forceinline__ float bf2f(unsigned short u) {
    return __uint_as_float(((unsigned int)u) << 16);
}
__device__ __forceinline__ float sigf(float x) {
    return 1.f / (1.f + __expf(-x));
}
__device__ __forceinline__ float tanhfast(float x) {
    return 2.f / (1.f + __expf(-2.f * x)) - 1.f;
}

// ---------------------------------------------------------------------------
// Prep A: Wlt[n][k] bf16, n=0..255, k=0..543:  Wlt[n][k] = W_lin[k][n] (k<536)
// Tiled transpose via LDS; coalesced loads and 16B stores.
// grid = 17 (k-tiles of 32) x 4 (n-tiles of 64) = 68 blocks, 256 thr.
// ---------------------------------------------------------------------------
__global__ __launch_bounds__(256) void k_prepwl(
    const float* __restrict__ W_lin, short* __restrict__ Wlt)
{
    const int tid = threadIdx.x;
    const int kt = blockIdx.x >> 2;      // 0..16
    const int nt = blockIdx.x & 3;       // 0..3
    const int k0 = kt * 32, n0 = nt * 64;

    __shared__ float tile[32][65];

    #pragma unroll
    for (int it = 0; it < 8; ++it) {
        const int idx = tid + it * 256;
        const int kk = idx >> 6, nn = idx & 63;
        const int k = k0 + kk;
        tile[kk][nn] = (k < WLROWS) ? W_lin[(size_t)k * E_DIM + n0 + nn] : 0.f;
    }
    __syncthreads();

    const int n  = tid >> 2;
    const int kg = tid & 3;
    int4 v;
    int* vi = (int*)&v;
    #pragma unroll
    for (int j = 0; j < 4; ++j) {
        int lo = f2bf(tile[kg * 8 + 2 * j][n]) & 0xffff;
        int hi = f2bf(tile[kg * 8 + 2 * j + 1][n]) & 0xffff;
        vi[j] = lo | (hi << 16);
    }
    *(int4*)(Wlt + (size_t)(n0 + n) * KPAD + k0 + kg * 8) = v;
}

// ---------------------------------------------------------------------------
// Prep B: Wt[n][k] (bf16, k=0..511) = [K;R][k][n]  (k<256 -> K, else R)
// ---------------------------------------------------------------------------
__global__ __launch_bounds__(256) void k_prep(
    const float* __restrict__ K, const float* __restrict__ R,
    short* __restrict__ Wt)
{
    const int tid = threadIdx.x;
    const int kt = blockIdx.x & 7;
    const int nt = blockIdx.x >> 3;
    const int k0 = kt * 64, n0 = nt * 64;

    __shared__ float tile[64][65];

    const int nloc_r = tid & 63;
    for (int kloc = tid >> 6; kloc < 64; kloc += 4) {
        const int k = k0 + kloc;
        float v = (k < 256) ? K[(size_t)k * G_DIM + n0 + nloc_r]
                            : R[(size_t)(k - 256) * G_DIM + n0 + nloc_r];
        tile[kloc][nloc_r] = v;
    }
    __syncthreads();

    const int nloc = tid >> 2;
    const int kc   = (tid & 3) * 16;
    int* dst = (int*)(Wt + (size_t)(n0 + nloc) * 512 + k0 + kc);
    #pragma unroll
    for (int j = 0; j < 8; ++j) {
        int lo = f2bf(tile[kc + 2 * j][nloc]) & 0xffff;
        int hi = f2bf(tile[kc + 2 * j + 1][nloc]) & 0xffff;
        dst[j] = lo | (hi << 16);
    }
}

// ---------------------------------------------------------------------------
// Fused embed + xz GEMM for one t-chunk.
// Block: 32 (n,t) rows. Phase 1: scatter one-hot (+aux cols) into LDS.
// Phase 2: xs = relu(onehot[32x544] @ Wlt^T[544x256] + b_lin)  (MFMA, ->LDS)
// Phase 3: xz = xs[32x256] @ Wt_K^T[256x1024]                  (MFMA, ->gmem)
// 512 threads (8 waves). Wave w: phase2 cols w*32+..., phase3 cols w*128+...
// ---------------------------------------------------------------------------
__global__ __launch_bounds__(512) void k_fused(
    const int* __restrict__ code, const float* __restrict__ aux,
    const short* __restrict__ Wlt, const float* __restrict__ b_lin,
    const short* __restrict__ Wt, short* __restrict__ xzb, int t0)
{
    const int tid  = threadIdx.x;
    const int w    = tid >> 6;
    const int lane = tid & 63;
    const int lr   = lane & 15;
    const int p    = lane >> 4;
    const int m0   = blockIdx.x * MBLK;

    __shared__ __align__(16) short oh[MBLK][552];   // one-hot + aux, 35.3 KB
    __shared__ __align__(16) short xs[MBLK][264];   // relu(x) tile, 16.9 KB
    __shared__ int s_nt[MBLK];

    // ---- zero one-hot ----
    for (int i = tid; i < (MBLK * 552) / 8; i += 512)
        ((int4*)&oh[0][0])[i] = (int4){0, 0, 0, 0};
    if (tid < MBLK) {
        const int m = m0 + tid;
        const int n = m / TCHUNK;
        const int tl = m - n * TCHUNK;
        s_nt[tid] = n * T_STEPS + t0 + tl;
    }
    __syncthreads();

    // ---- scatter codes (presence; duplicates idempotent; drop c==0) ----
    for (int i = tid; i < MBLK * NCODES; i += 512) {
        const int r = i / NCODES;
        const int j = i - r * NCODES;
        const int c = code[(size_t)s_nt[r] * NCODES + j];
        if (c > 0) ((unsigned short*)&oh[0][0])[r * 552 + (c - 1)] = 0x3F80;
    }
    // ---- aux columns ----
    if (tid < MBLK * AUXD) {
        const int r = tid / AUXD;
        const int a = tid - r * AUXD;
        oh[r][MH + a] = f2bf(aux[(size_t)s_nt[r] * AUXD + a]);
    }
    __syncthreads();

    // ---- Phase 2: xs = relu(oh @ Wlt^T + b_lin), wave cols w*32..w*32+31 ----
    {
        f32x4 acc[2][2];
        #pragma unroll
        for (int rb = 0; rb < 2; ++rb)
            #pragma unroll
            for (int cb = 0; cb < 2; ++cb)
                acc[rb][cb] = (f32x4){0.f, 0.f, 0.f, 0.f};

        for (int kk = 0; kk < 17; ++kk) {
            short8 a0 = *(const short8*)&oh[lr][kk * 32 + p * 8];
            short8 a1 = *(const short8*)&oh[16 + lr][kk * 32 + p * 8];
            #pragma unroll
            for (int cb = 0; cb < 2; ++cb) {
                short8 bf = *(const short8*)(Wlt +
                    (size_t)(w * 32 + cb * 16 + lr) * KPAD + kk * 32 + p * 8);
                acc[0][cb] = __builtin_amdgcn_mfma_f32_16x16x32_bf16(a0, bf, acc[0][cb], 0, 0, 0);
                acc[1][cb] = __builtin_amdgcn_mfma_f32_16x16x32_bf16(a1, bf, acc[1][cb], 0, 0, 0);
            }
        }
        float bias[2];
        #pragma unroll
        for (int cb = 0; cb < 2; ++cb) bias[cb] = b_lin[w * 32 + cb * 16 + lr];
        __syncthreads();   // oh reads done (also before xs writes vs nothing)
        #pragma unroll
        for (int rb = 0; rb < 2; ++rb)
            #pragma unroll
            for (int cb = 0; cb < 2; ++cb)
                #pragma unroll
                for (int rr = 0; rr < 4; ++rr)
                    xs[rb * 16 + p * 4 + rr][w * 32 + cb * 16 + lr] =
                        f2bf(fmaxf(acc[rb][cb][rr] + bias[cb], 0.f));
        __syncthreads();
    }

    // ---- Phase 3: xz = xs @ Wt_K^T, wave cols w*128..w*128+127 ----
    {
        f32x4 acc[2][8];
        #pragma unroll
        for (int rb = 0; rb < 2; ++rb)
            #pragma unroll
            for (int cb = 0; cb < 8; ++cb)
                acc[rb][cb] = (f32x4){0.f, 0.f, 0.f, 0.f};

        for (int kb = 0; kb < 8; ++kb) {
            short8 a0 = *(const short8*)&xs[lr][kb * 32 + p * 8];
            short8 a1 = *(const short8*)&xs[16 + lr][kb * 32 + p * 8];
            short8 bf[8];
            #pragma unroll
            for (int cb = 0; cb < 8; ++cb)
                bf[cb] = *(const short8*)(Wt +
                    (size_t)(w * 128 + cb * 16 + lr) * 512 + kb * 32 + p * 8);
            #pragma unroll
            for (int cb = 0; cb < 8; ++cb) {
                acc[0][cb] = __builtin_amdgcn_mfma_f32_16x16x32_bf16(a0, bf[cb], acc[0][cb], 0, 0, 0);
                acc[1][cb] = __builtin_amdgcn_mfma_f32_16x16x32_bf16(a1, bf[cb], acc[1][cb], 0, 0, 0);
            }
        }
        #pragma unroll
        for (int rb = 0; rb < 2; ++rb)
            #pragma unroll
            for (int cb = 0; cb < 8; ++cb)
                #pragma unroll
                for (int rr = 0; rr < 4; ++rr)
                    xzb[(size_t)(m0 + rb * 16 + p * 4 + rr) * G_DIM +
                        w * 128 + cb * 16 + lr] = f2bf(acc[rb][cb][rr]);
    }
}

// ---------------------------------------------------------------------------
// Recurrence for one t-chunk (unchanged from R3, validated).
// ---------------------------------------------------------------------------
__global__ __launch_bounds__(512) void k_rec(
    const short* __restrict__ xz, const int* __restrict__ length,
    const short* __restrict__ Wt, const float* __restrict__ b,
    short* __restrict__ h_state, float* __restrict__ c_state,
    float* __restrict__ xlast, int t0)
{
    const int tid  = threadIdx.x;
    const int w    = tid >> 6;
    const int lane = tid & 63;
    const int lr   = lane & 15;
    const int p    = lane >> 4;
    const int r0   = blockIdx.x * BM;

    __shared__ __align__(16) short h_s[BM][264];
    __shared__ int s_len[BM];
    __shared__ int s_maxlen;

    if (tid < BM) s_len[tid] = length[r0 + tid];
    __syncthreads();
    if (tid == 0) {
        int m = 0;
        for (int r2 = 0; r2 < BM; ++r2) m = max(m, s_len[r2]);
        s_maxlen = m;
    }
    __syncthreads();
    const int mlen = s_maxlen;
    if (mlen <= t0) return;
    const int steps = min(TCHUNK, mlen - t0);

    const int ecol = w * 32 + lr;

    float creg[8];
    if (t0 == 0) {
        for (int i = tid; i < BM * 264; i += 512) (&h_s[0][0])[i] = 0;
        #pragma unroll
        for (int i = 0; i < 8; ++i) creg[i] = 0.f;
    } else {
        for (int i = tid; i < BM * E_DIM; i += 512) {
            int r2 = i >> 8, e = i & 255;
            h_s[r2][e] = h_state[(size_t)(r0 + r2) * E_DIM + e];
        }
        #pragma unroll
        for (int eb = 0; eb < 2; ++eb)
            #pragma unroll
            for (int rr = 0; rr < 4; ++rr)
                creg[eb * 4 + rr] =
                    c_state[(size_t)(r0 + p * 4 + rr) * E_DIM + ecol + eb * 16];
    }
    __syncthreads();

    int len_r[4];
    #pragma unroll
    for (int rr = 0; rr < 4; ++rr) len_r[rr] = s_len[p * 4 + rr];

    float bias[8];
    #pragma unroll
    for (int eb = 0; eb < 2; ++eb)
        #pragma unroll
        for (int g = 0; g < 4; ++g)
            bias[eb * 4 + g] = b[g * 256 + ecol + eb * 16];

    const short* wb = Wt + (size_t)(w * 32 + lr) * 512 + 256 + p * 8; // R-half

    for (int tl = 0; tl < steps; ++tl) {
        const int t = t0 + tl;

        short8 a[8];
        #pragma unroll
        for (int kk = 0; kk < 8; ++kk)
            a[kk] = *(const short8*)(&h_s[lr][kk * 32 + p * 8]);

        f32x4 acc[8];
        #pragma unroll
        for (int f = 0; f < 8; ++f) {
            const int eb = f >> 2, g = f & 3;
            #pragma unroll
            for (int rr = 0; rr < 4; ++rr) {
                const size_t m = (size_t)(r0 + p * 4 + rr) * TCHUNK + tl;
                acc[f][rr] = bf2f((unsigned short)
                    xz[m * G_DIM + g * 256 + w * 32 + eb * 16 + lr]);
            }
        }

        short8 bA[8], bB[8];
        #pragma unroll
        for (int f = 0; f < 8; ++f) {
            const int eb = f >> 2, g = f & 3;
            bA[f] = *(const short8*)(wb + (size_t)(g * 256 + eb * 16) * 512);
        }
        #pragma unroll
        for (int kp = 0; kp < 4; ++kp) {
            const int k_e = kp * 2, k_o = kp * 2 + 1;
            #pragma unroll
            for (int f = 0; f < 8; ++f) {
                const int eb = f >> 2, g = f & 3;
                bB[f] = *(const short8*)(wb +
                    (size_t)(g * 256 + eb * 16) * 512 + k_o * 32);
            }
            #pragma unroll
            for (int f = 0; f < 8; ++f)
                acc[f] = __builtin_amdgcn_mfma_f32_16x16x32_bf16(
                    a[k_e], bA[f], acc[f], 0, 0, 0);
            if (kp < 3) {
                #pragma unroll
                for (int f = 0; f < 8; ++f) {
                    const int eb = f >> 2, g = f & 3;
                    bA[f] = *(const short8*)(wb +
                        (size_t)(g * 256 + eb * 16) * 512 + (k_e + 2) * 32);
                }
            }
            #pragma unroll
            for (int f = 0; f < 8; ++f)
                acc[f] = __builtin_amdgcn_mfma_f32_16x16x32_bf16(
                    a[k_o], bB[f], acc[f], 0, 0, 0);
        }

        short hnew[8];
        float hout[8];
        #pragma unroll
        for (int eb = 0; eb < 2; ++eb) {
            #pragma unroll
            for (int rr = 0; rr < 4; ++rr) {
                float zi = acc[eb * 4 + 0][rr] + bias[eb * 4 + 0];
                float zf = acc[eb * 4 + 1][rr] + bias[eb * 4 + 1];
                float zg = acc[eb * 4 + 2][rr] + bias[eb * 4 + 2];
                float zo = acc[eb * 4 + 3][rr] + bias[eb * 4 + 3];
                float ig = sigf(zi), fg = sigf(zf);
                float gg = tanhfast(zg), og = sigf(zo);
                float cc = fg * creg[eb * 4 + rr] + ig * gg;
                float hh = og * tanhfast(cc);
                creg[eb * 4 + rr] = cc;
                hnew[eb * 4 + rr] = f2bf(hh);
                hout[eb * 4 + rr] = hh;
            }
        }
        __syncthreads();
        #pragma unroll
        for (int eb = 0; eb < 2; ++eb) {
            #pragma unroll
            for (int rr = 0; rr < 4; ++rr) {
                const int m = p * 4 + rr;
                const int e = ecol + eb * 16;
                h_s[m][e] = hnew[eb * 4 + rr];
                if (t == len_r[rr] - 1)
                    xlast[(size_t)(r0 + m) * E_DIM + e] = hout[eb * 4 + rr];
            }
        }
        __syncthreads();
    }

    for (int i = tid; i < BM * E_DIM; i += 512) {
        int r2 = i >> 8, e = i & 255;
        h_state[(size_t)(r0 + r2) * E_DIM + e] = h_s[r2][e];
    }
    #pragma unroll
    for (int eb = 0; eb < 2; ++eb)
        #pragma unroll
        for (int rr = 0; rr < 4; ++rr)
            c_state[(size_t)(r0 + p * 4 + rr) * E_DIM + ecol + eb * 16] =
                creg[eb * 4 + rr];
}

// ---------------------------------------------------------------------------
// Head MLP + L2 normalize (unchanged).
// ---------------------------------------------------------------------------
__global__ __launch_bounds__(256) void k_head(
    const float* __restrict__ xlast,
    const float* __restrict__ W0, const float* __restrict__ b0,
    const float* __restrict__ W1, const float* __restrict__ b1,
    float* __restrict__ out)
{
    const int n = blockIdx.x;
    const int j = threadIdx.x;

    __shared__ __align__(16) float xsh[E_DIM];
    __shared__ __align__(16) float y0[E_DIM];
    __shared__ float part[4];

    xsh[j] = xlast[(size_t)n * E_DIM + j];
    __syncthreads();

    float acc = b0[j];
    for (int k4 = 0; k4 < E_DIM; k4 += 4) {
        float4 xv = *reinterpret_cast<const float4*>(&xsh[k4]);
        #pragma unroll
        for (int kk = 0; kk < 4; ++kk)
            acc += (&xv.x)[kk] * W0[(size_t)(k4 + kk) * E_DIM + j];
    }
    y0[j] = fmaxf(acc, 0.f);
    __syncthreads();

    acc = b1[j];
    for (int k4 = 0; k4 < E_DIM; k4 += 4) {
        float4 yv = *reinterpret_cast<const float4*>(&y0[k4]);
        #pragma unroll
        for (int kk = 0; kk < 4; ++kk)
            acc += (&yv.x)[kk] * W1[(size_t)(k4 + kk) * E_DIM + j];
    }

    float sq = acc * acc;
    #pragma unroll
    for (int off = 32; off > 0; off >>= 1)
        sq += __shfl_xor(sq, off, 64);
    if ((j & 63) == 0) part[j >> 6] = sq;
    __syncthreads();
    float total = part[0] + part[1] + part[2] + part[3];

    out[(size_t)n * E_DIM + j] = acc * rsqrtf(total);
}

// ---------------------------------------------------------------------------
extern "C" void kernel_launch(void* const* d_in, const int* in_sizes, int n_in,
                              void* d_out, int out_size, void* d_ws, size_t ws_size,
                              hipStream_t stream) {
    const int*   code   = (const int*)  d_in[0];
    const float* aux    = (const float*)d_in[1];
    const int*   length = (const int*)  d_in[2];
    // d_in[3] = is_training (ignored)
    const float* W_lin  = (const float*)d_in[4];
    const float* b_lin  = (const float*)d_in[5];
    const float* K      = (const float*)d_in[6];
    const float* R      = (const float*)d_in[7];
    const float* b      = (const float*)d_in[8];
    const float* W0     = (const float*)d_in[9];
    const float* b0     = (const float*)d_in[10];
    const float* W1     = (const float*)d_in[11];
    const float* b1     = (const float*)d_in[12];
    float* out = (float*)d_out;

    // workspace layout (bytes, 16B aligned); total ~48.5 MB
    char* ws = (char*)d_ws;
    short* Wt      = (short*)(ws + 0);            //  1,048,576
    short* Wlt     = (short*)(ws + 1048576);      //    278,528
    float* xlast   = (float*)(ws + 1327104);      //  2,097,152
    short* h_state = (short*)(ws + 3424256);      //  1,048,576
    float* c_state = (float*)(ws + 4472832);      //  2,097,152
    short* xzb     = (short*)(ws + 6569984);      // 41,943,040

    k_prepwl<<<68,  256, 0, stream>>>(W_lin, Wlt);
    k_prep  <<<128, 256, 0, stream>>>(K, R, Wt);

    for (int c = 0; c < T_STEPS / TCHUNK; ++c) {
        const int t0 = c * TCHUNK;
        k_fused<<<N_BATCH * TCHUNK / MBLK, 512, 0, stream>>>(
            code, aux, Wlt, b_lin, Wt, xzb, t0);
        k_rec<<<N_BATCH / BM, 512, 0, stream>>>(xzb, length, Wt, b,
                                                h_state, c_state, xlast, t0);
    }

    k_head<<<N_BATCH, 256, 0, stream>>>(xlast, W0, b0, W1, b1, out);
}